// Round 2
// baseline (594.441 us; speedup 1.0000x reference)
//
#include <hip/hip_runtime.h>
#include <hip/hip_bf16.h>
#include <cstdint>

// ---------------------------------------------------------------------------
// BitLinear GLU: x[8192,2048] f32, W[8192,2048] f32 -> out[8192,4096] f32
//   normed = layernorm(x) (no affine, eps 1e-5)
//   gamma  = max|normed| (global), wg = mean|W| (global)
//   q = clip(normed*128/gamma, +-(128-1e-5))   (f16 in ws)
//   wq = clip(round(W/(wg+1e-7)), -1, 1)       (f16 in ws, ternary)
//   C = q @ wq^T * (gamma*wg/128);  out = C[:, :4096] * silu(C[:, 4096:])
// ---------------------------------------------------------------------------

#define N_TOK   8192
#define DIMIN   2048
#define DIMOUT  8192
#define NOUT    4096   // DIMOUT/2
#define QCLIP   127.99999f

typedef _Float16 f16x8 __attribute__((ext_vector_type(8)));
typedef _Float16 f16x4 __attribute__((ext_vector_type(4)));
typedef float    f32x4 __attribute__((ext_vector_type(4)));

// ---------------- row stats: mean, rstd, atomicMax(gamma) -------------------
__global__ void rowstats_k(const float* __restrict__ x, float* __restrict__ mean,
                           float* __restrict__ rstd, float* __restrict__ sc) {
    __shared__ float sh[16];
    const int t = threadIdx.x;
    const float4* xr = (const float4*)(x + (size_t)blockIdx.x * DIMIN);
    float4 a = xr[2 * t];
    float4 b = xr[2 * t + 1];
    float s = (a.x + a.y) + (a.z + a.w) + ((b.x + b.y) + (b.z + b.w));
#pragma unroll
    for (int o = 32; o > 0; o >>= 1) s += __shfl_down(s, o, 64);
    if ((t & 63) == 0) sh[t >> 6] = s;
    __syncthreads();
    const float mu = (sh[0] + sh[1] + sh[2] + sh[3]) * (1.0f / DIMIN);

    float d0 = a.x - mu, d1 = a.y - mu, d2 = a.z - mu, d3 = a.w - mu;
    float d4 = b.x - mu, d5 = b.y - mu, d6 = b.z - mu, d7 = b.w - mu;
    float ss = d0*d0 + d1*d1 + d2*d2 + d3*d3 + d4*d4 + d5*d5 + d6*d6 + d7*d7;
    float mx = fmaxf(fmaxf(fmaxf(fabsf(d0), fabsf(d1)), fmaxf(fabsf(d2), fabsf(d3))),
                     fmaxf(fmaxf(fabsf(d4), fabsf(d5)), fmaxf(fabsf(d6), fabsf(d7))));
#pragma unroll
    for (int o = 32; o > 0; o >>= 1) {
        ss += __shfl_down(ss, o, 64);
        mx = fmaxf(mx, __shfl_down(mx, o, 64));
    }
    __syncthreads();  // sh reuse
    if ((t & 63) == 0) { sh[t >> 6] = ss; sh[8 + (t >> 6)] = mx; }
    __syncthreads();
    if (t == 0) {
        float var = (sh[0] + sh[1] + sh[2] + sh[3]) * (1.0f / DIMIN);
        float r = rsqrtf(var + 1e-5f);
        mean[blockIdx.x] = mu;
        rstd[blockIdx.x] = r;
        float g = fmaxf(fmaxf(sh[8], sh[9]), fmaxf(sh[10], sh[11])) * r;
        atomicMax((unsigned int*)sc, __float_as_uint(g));  // g >= 0
    }
}

// ---------------- sum |W| ---------------------------------------------------
__global__ void wsum_k(const float* __restrict__ w, float* __restrict__ wsum) {
    float acc = 0.0f;
    const float4* w4 = (const float4*)w;
    for (unsigned i = blockIdx.x * 256u + threadIdx.x; i < 4194304u; i += 262144u) {
        float4 v = w4[i];
        acc += (fabsf(v.x) + fabsf(v.y)) + (fabsf(v.z) + fabsf(v.w));
    }
    __shared__ float sh[4];
#pragma unroll
    for (int o = 32; o > 0; o >>= 1) acc += __shfl_down(acc, o, 64);
    if ((threadIdx.x & 63) == 0) sh[threadIdx.x >> 6] = acc;
    __syncthreads();
    if (threadIdx.x == 0) atomicAdd(wsum, (sh[0] + sh[1]) + (sh[2] + sh[3]));
}

// ---------------- derive scalars: sc[2]=128/gamma sc[3]=1/(wg+eps) sc[4]=s --
__global__ void scalars_k(float* __restrict__ sc) {
    float g  = sc[0];                            // gamma (bits stored via atomicMax)
    float wg = sc[1] * (1.0f / 16777216.0f);     // mean |W|
    sc[2] = 128.0f / g;
    sc[3] = 1.0f / (wg + 1e-7f);
    sc[4] = g * wg * (1.0f / 128.0f);
}

// ---------------- quantize activations to f16 -------------------------------
__global__ void quantA_k(const float* __restrict__ x, const float* __restrict__ mean,
                         const float* __restrict__ rstd, const float* __restrict__ sc,
                         _Float16* __restrict__ q) {
    const float aq = sc[2];
    for (unsigned i = blockIdx.x * 256u + threadIdx.x; i < 4194304u; i += 524288u) {
        int row = (int)(i >> 9);                 // 512 float4 per row
        float k = rstd[row] * aq;
        float mu = mean[row];
        float4 v = ((const float4*)x)[i];
        f16x4 o;
        o.x = (_Float16)fminf(fmaxf((v.x - mu) * k, -QCLIP), QCLIP);
        o.y = (_Float16)fminf(fmaxf((v.y - mu) * k, -QCLIP), QCLIP);
        o.z = (_Float16)fminf(fmaxf((v.z - mu) * k, -QCLIP), QCLIP);
        o.w = (_Float16)fminf(fmaxf((v.w - mu) * k, -QCLIP), QCLIP);
        ((f16x4*)q)[i] = o;
    }
}

// ---------------- ternarize weights to f16 ----------------------------------
__global__ void ternW_k(const float* __restrict__ w, const float* __restrict__ sc,
                        _Float16* __restrict__ q) {
    const float invw = sc[3];
    for (unsigned i = blockIdx.x * 256u + threadIdx.x; i < 4194304u; i += 524288u) {
        float4 v = ((const float4*)w)[i];
        f16x4 o;
        o.x = (_Float16)fminf(fmaxf(rintf(v.x * invw), -1.0f), 1.0f);
        o.y = (_Float16)fminf(fmaxf(rintf(v.y * invw), -1.0f), 1.0f);
        o.z = (_Float16)fminf(fmaxf(rintf(v.z * invw), -1.0f), 1.0f);
        o.w = (_Float16)fminf(fmaxf(rintf(v.w * invw), -1.0f), 1.0f);
        ((f16x4*)q)[i] = o;
    }
}

// ---------------- fused GEMM (both halves) + SiLU gate ----------------------
__device__ __forceinline__ void ld16(const _Float16* g, _Float16* l) {
    // proper addrspacecast (NOT inttoptr): generic->AS1 / generic->AS3
    __builtin_amdgcn_global_load_lds(
        (const __attribute__((address_space(1))) unsigned int*)g,
        (__attribute__((address_space(3))) unsigned int*)l, 16, 0, 0);
}

__global__ __launch_bounds__(256, 2) void gemm_glu_k(
    const _Float16* __restrict__ Aq, const _Float16* __restrict__ Wq,
    const float* __restrict__ sc, float* __restrict__ out) {
    // Block tile: 128 rows (m) x 128 cols of OUT; needs C_h (W rows n0..)
    // and C_g (W rows n0+4096..).  BK=32.  LDS 3x8KB, single-buffered (m97).
    __shared__ __align__(16) _Float16 smem[3 * 4096];
    _Float16* As = smem;
    _Float16* Bh = smem + 4096;
    _Float16* Bg = smem + 8192;

    const int tid  = threadIdx.x;
    const int wave = tid >> 6;
    const int lane = tid & 63;
    const int m0 = blockIdx.y << 7;
    const int n0 = blockIdx.x << 7;

    // staging: lane covers 16B at row srow(+64), k-halves scol
    const int srow = wave * 16 + (lane >> 2);
    const int scol = (lane & 3) * 8;
    const _Float16* ga0 = Aq + (size_t)(m0 + srow) * DIMIN + scol;
    const _Float16* ga1 = ga0 + 64 * DIMIN;
    const _Float16* gh0 = Wq + (size_t)(n0 + srow) * DIMIN + scol;
    const _Float16* gh1 = gh0 + 64 * DIMIN;
    const _Float16* gg0 = Wq + (size_t)(n0 + NOUT + srow) * DIMIN + scol;
    const _Float16* gg1 = gg0 + 64 * DIMIN;

    _Float16* const da0 = As + wave * 512;          // wave-uniform LDS bases
    _Float16* const da1 = As + 2048 + wave * 512;
    _Float16* const dh0 = Bh + wave * 512;
    _Float16* const dh1 = Bh + 2048 + wave * 512;
    _Float16* const dg0 = Bg + wave * 512;
    _Float16* const dg1 = Bg + 2048 + wave * 512;

    const int wm = (wave >> 1) * 64;   // wave's 64x64 quadrant
    const int wn = (wave & 1) * 64;
    const int fr = lane & 15;
    const int fk = (lane >> 4) * 8;

    f32x4 zero = {0.0f, 0.0f, 0.0f, 0.0f};
    f32x4 ah[4][4], ag[4][4];
#pragma unroll
    for (int i = 0; i < 4; ++i)
#pragma unroll
        for (int j = 0; j < 4; ++j) { ah[i][j] = zero; ag[i][j] = zero; }

    for (int kk = 0; kk < DIMIN / 32; ++kk) {
        __syncthreads();
        ld16(ga0, da0); ld16(ga1, da1);
        ld16(gh0, dh0); ld16(gh1, dh1);
        ld16(gg0, dg0); ld16(gg1, dg1);
        ga0 += 32; ga1 += 32; gh0 += 32; gh1 += 32; gg0 += 32; gg1 += 32;
        __syncthreads();

        f16x8 af[4], bhf[4], bgf[4];
#pragma unroll
        for (int t = 0; t < 4; ++t) {
            af[t]  = *(const f16x8*)(As + (wm + t * 16 + fr) * 32 + fk);
            bhf[t] = *(const f16x8*)(Bh + (wn + t * 16 + fr) * 32 + fk);
            bgf[t] = *(const f16x8*)(Bg + (wn + t * 16 + fr) * 32 + fk);
        }
#pragma unroll
        for (int mt = 0; mt < 4; ++mt)
#pragma unroll
            for (int nt = 0; nt < 4; ++nt) {
                ah[mt][nt] = __builtin_amdgcn_mfma_f32_16x16x32_f16(af[mt], bhf[nt], ah[mt][nt], 0, 0, 0);
                ag[mt][nt] = __builtin_amdgcn_mfma_f32_16x16x32_f16(af[mt], bgf[nt], ag[mt][nt], 0, 0, 0);
            }
    }

    const float s = sc[4];
    const int er = (lane >> 4) * 4;   // C/D: col = lane&15, row = (lane>>4)*4 + r
#pragma unroll
    for (int mt = 0; mt < 4; ++mt)
#pragma unroll
        for (int nt = 0; nt < 4; ++nt)
#pragma unroll
            for (int r = 0; r < 4; ++r) {
                int m = m0 + wm + mt * 16 + er + r;
                int n = n0 + wn + nt * 16 + fr;
                float h = ah[mt][nt][r] * s;
                float g = ag[mt][nt][r] * s;
                float o = h * g / (1.0f + __expf(-g));   // h * silu(g)
                out[(size_t)m * NOUT + n] = o;
            }
}

// ---------------------------------------------------------------------------
extern "C" void kernel_launch(void* const* d_in, const int* in_sizes, int n_in,
                              void* d_out, int out_size, void* d_ws, size_t ws_size,
                              hipStream_t stream) {
    const float* x = (const float*)d_in[0];
    const float* w = (const float*)d_in[1];
    float* out = (float*)d_out;   // reference output dtype is float32

    char* ws = (char*)d_ws;
    float* mean = (float*)ws;                       //  32 KB
    float* rstd = (float*)(ws + 32768);             //  32 KB
    float* sc   = (float*)(ws + 65536);             //  [0]=gamma [1]=sum|W| [2]=128/g [3]=1/(wg+eps) [4]=s
    _Float16* qA = (_Float16*)(ws + 131072);                  // 32 MB
    _Float16* wB = (_Float16*)(ws + 131072 + 33554432);       // 32 MB

    hipMemsetAsync(sc, 0, 8, stream);  // gamma-bits = 0, wsum = 0

    rowstats_k<<<N_TOK, 256, 0, stream>>>(x, mean, rstd, sc);
    wsum_k<<<1024, 256, 0, stream>>>(w, sc + 1);
    scalars_k<<<1, 1, 0, stream>>>(sc);
    quantA_k<<<2048, 256, 0, stream>>>(x, mean, rstd, sc, qA);
    ternW_k<<<2048, 256, 0, stream>>>(w, sc, wB);

    dim3 grid(NOUT / 128, N_TOK / 128);  // 32 x 64
    gemm_glu_k<<<grid, 256, 0, stream>>>(qA, wB, sc, out);
}

// Round 3
// 490.744 us; speedup vs baseline: 1.2113x; 1.2113x over previous
//
#include <hip/hip_runtime.h>
#include <hip/hip_bf16.h>
#include <cstdint>

// ---------------------------------------------------------------------------
// BitLinear GLU: x[8192,2048] f32, W[8192,2048] f32 -> out[8192,4096] f32
//   Key identity: out = (normed @ w_bin^T) * w_gamma  -- input_gamma cancels
//   (clip at +-128 only binds within 1e-7 of the global max: delta ~ 5e-9).
//   K1: per-row LN -> normed (f16, ws)  +  sum|W| (atomic)
//   K2: w_bin = clip(round(W/(wg+1e-7)), -1, 1)  (f16, ws)
//   K3: C = normed @ w_bin^T; out = C_h * silu(C_g) * wg   (fused dual-half)
// ---------------------------------------------------------------------------

#define N_TOK   8192
#define DIMIN   2048
#define DIMOUT  8192
#define NOUT    4096   // DIMOUT/2
#define W_ELEMS 16777216.0f

typedef _Float16 f16x8 __attribute__((ext_vector_type(8)));
typedef _Float16 f16x4 __attribute__((ext_vector_type(4)));
typedef float    f32x4 __attribute__((ext_vector_type(4)));

// ---------------- K1: fused rownorm->f16 + sum|W| ---------------------------
__global__ __launch_bounds__(256) void prep_k(
    const float* __restrict__ x, const float* __restrict__ w,
    _Float16* __restrict__ qA, float* __restrict__ sc) {
    const int b = blockIdx.x;
    const int t = threadIdx.x;
    if (b < N_TOK) {
        __shared__ float sh[8];
        const float4* xr = (const float4*)(x + (size_t)b * DIMIN);
        float4 a = xr[2 * t];
        float4 c = xr[2 * t + 1];
        float s = (a.x + a.y) + (a.z + a.w) + ((c.x + c.y) + (c.z + c.w));
#pragma unroll
        for (int o = 32; o > 0; o >>= 1) s += __shfl_down(s, o, 64);
        if ((t & 63) == 0) sh[t >> 6] = s;
        __syncthreads();
        const float mu = (sh[0] + sh[1] + sh[2] + sh[3]) * (1.0f / DIMIN);

        float d0 = a.x - mu, d1 = a.y - mu, d2 = a.z - mu, d3 = a.w - mu;
        float d4 = c.x - mu, d5 = c.y - mu, d6 = c.z - mu, d7 = c.w - mu;
        float ss = d0*d0 + d1*d1 + d2*d2 + d3*d3 + d4*d4 + d5*d5 + d6*d6 + d7*d7;
#pragma unroll
        for (int o = 32; o > 0; o >>= 1) ss += __shfl_down(ss, o, 64);
        if ((t & 63) == 0) sh[4 + (t >> 6)] = ss;
        __syncthreads();
        const float var = (sh[4] + sh[5] + sh[6] + sh[7]) * (1.0f / DIMIN);
        const float r = rsqrtf(var + 1e-5f);
        f16x8 o;
        o[0] = (_Float16)(d0 * r); o[1] = (_Float16)(d1 * r);
        o[2] = (_Float16)(d2 * r); o[3] = (_Float16)(d3 * r);
        o[4] = (_Float16)(d4 * r); o[5] = (_Float16)(d5 * r);
        o[6] = (_Float16)(d6 * r); o[7] = (_Float16)(d7 * r);
        ((f16x8*)(qA + (size_t)b * DIMIN))[t] = o;
    } else {
        // sum |W| over 1024 blocks
        float acc = 0.0f;
        const float4* w4 = (const float4*)w;
        for (unsigned i = (unsigned)(b - N_TOK) * 256u + t; i < 4194304u; i += 262144u) {
            float4 v = w4[i];
            acc += (fabsf(v.x) + fabsf(v.y)) + (fabsf(v.z) + fabsf(v.w));
        }
        __shared__ float shw[4];
#pragma unroll
        for (int o = 32; o > 0; o >>= 1) acc += __shfl_down(acc, o, 64);
        if ((t & 63) == 0) shw[t >> 6] = acc;
        __syncthreads();
        if (t == 0) atomicAdd(sc, (shw[0] + shw[1]) + (shw[2] + shw[3]));
    }
}

// ---------------- K2: ternarize weights to f16 ------------------------------
__global__ void ternW_k(const float* __restrict__ w, const float* __restrict__ sc,
                        _Float16* __restrict__ q) {
    const float wg = sc[0] * (1.0f / W_ELEMS);
    const float invw = 1.0f / (wg + 1e-7f);
    for (unsigned i = blockIdx.x * 256u + threadIdx.x; i < 4194304u; i += 524288u) {
        float4 v = ((const float4*)w)[i];
        f16x4 o;
        o.x = (_Float16)fminf(fmaxf(rintf(v.x * invw), -1.0f), 1.0f);
        o.y = (_Float16)fminf(fmaxf(rintf(v.y * invw), -1.0f), 1.0f);
        o.z = (_Float16)fminf(fmaxf(rintf(v.z * invw), -1.0f), 1.0f);
        o.w = (_Float16)fminf(fmaxf(rintf(v.w * invw), -1.0f), 1.0f);
        ((f16x4*)q)[i] = o;
    }
}

// ---------------- K3: fused GEMM (both halves) + SiLU gate ------------------
__device__ __forceinline__ void ld16(const _Float16* g, _Float16* l) {
    __builtin_amdgcn_global_load_lds(
        (const __attribute__((address_space(1))) unsigned int*)g,
        (__attribute__((address_space(3))) unsigned int*)l, 16, 0, 0);
}

__global__ __launch_bounds__(256, 2) void gemm_glu_k(
    const _Float16* __restrict__ Aq, const _Float16* __restrict__ Wq,
    const float* __restrict__ sc, float* __restrict__ out) {
    // 128 (m) x 128 (n of OUT) block tile; C_h from W rows n0.., C_g from
    // W rows n0+4096.. ; BK=32; LDS 3x8KB single-buffered (m97 structure).
    // 16B-granule XOR swizzle kills the 8-way bank conflict on frag reads:
    //   element (r, kg) stored at granule (kg ^ ((r>>1)&3)) of row r.
    __shared__ __align__(16) _Float16 smem[3 * 4096];
    _Float16* As = smem;
    _Float16* Bh = smem + 4096;
    _Float16* Bg = smem + 8192;

    const int tid  = threadIdx.x;
    const int wave = tid >> 6;
    const int lane = tid & 63;
    const int m0 = blockIdx.y << 7;
    const int n0 = blockIdx.x << 7;

    // staging: lane ell covers rows w*16 + (ell>>2); fetches k-group
    // (ell&3) ^ ((ell>>3)&3)  (the swizzle), 8 halfwords = 16B.
    const int srow = wave * 16 + (lane >> 2);
    const int scol = (((lane & 3) ^ ((lane >> 3) & 3)) << 3);
    const _Float16* ga0 = Aq + (size_t)(m0 + srow) * DIMIN + scol;
    const _Float16* ga1 = ga0 + 64 * DIMIN;
    const _Float16* gh0 = Wq + (size_t)(n0 + srow) * DIMIN + scol;
    const _Float16* gh1 = gh0 + 64 * DIMIN;
    const _Float16* gg0 = Wq + (size_t)(n0 + NOUT + srow) * DIMIN + scol;
    const _Float16* gg1 = gg0 + 64 * DIMIN;

    _Float16* const da0 = As + wave * 512;          // wave-uniform LDS bases
    _Float16* const da1 = As + 2048 + wave * 512;
    _Float16* const dh0 = Bh + wave * 512;
    _Float16* const dh1 = Bh + 2048 + wave * 512;
    _Float16* const dg0 = Bg + wave * 512;
    _Float16* const dg1 = Bg + 2048 + wave * 512;

    const int wm = (wave >> 1) * 64;   // wave's 64x64 quadrant
    const int wn = (wave & 1) * 64;
    const int fr = lane & 15;
    // un-swizzled k-group for fragment reads (per-lane constant):
    const int fswz = (((lane >> 4) ^ ((fr >> 1) & 3)) << 3);

    f32x4 zero = {0.0f, 0.0f, 0.0f, 0.0f};
    f32x4 ah[4][4], ag[4][4];
#pragma unroll
    for (int i = 0; i < 4; ++i)
#pragma unroll
        for (int j = 0; j < 4; ++j) { ah[i][j] = zero; ag[i][j] = zero; }

    for (int kk = 0; kk < DIMIN / 32; ++kk) {
        __syncthreads();
        ld16(ga0, da0); ld16(ga1, da1);
        ld16(gh0, dh0); ld16(gh1, dh1);
        ld16(gg0, dg0); ld16(gg1, dg1);
        ga0 += 32; ga1 += 32; gh0 += 32; gh1 += 32; gg0 += 32; gg1 += 32;
        __syncthreads();

        f16x8 af[4], bhf[4], bgf[4];
#pragma unroll
        for (int t = 0; t < 4; ++t) {
            af[t]  = *(const f16x8*)(As + (wm + t * 16 + fr) * 32 + fswz);
            bhf[t] = *(const f16x8*)(Bh + (wn + t * 16 + fr) * 32 + fswz);
            bgf[t] = *(const f16x8*)(Bg + (wn + t * 16 + fr) * 32 + fswz);
        }
#pragma unroll
        for (int mt = 0; mt < 4; ++mt)
#pragma unroll
            for (int nt = 0; nt < 4; ++nt) {
                ah[mt][nt] = __builtin_amdgcn_mfma_f32_16x16x32_f16(af[mt], bhf[nt], ah[mt][nt], 0, 0, 0);
                ag[mt][nt] = __builtin_amdgcn_mfma_f32_16x16x32_f16(af[mt], bgf[nt], ag[mt][nt], 0, 0, 0);
            }
    }

    const float s = sc[0] * (1.0f / W_ELEMS);   // w_gamma
    const int er = (lane >> 4) * 4;   // C/D: col = lane&15, row = (lane>>4)*4 + r
#pragma unroll
    for (int mt = 0; mt < 4; ++mt)
#pragma unroll
        for (int nt = 0; nt < 4; ++nt)
#pragma unroll
            for (int r = 0; r < 4; ++r) {
                int m = m0 + wm + mt * 16 + er + r;
                int n = n0 + wn + nt * 16 + fr;
                float h = ah[mt][nt][r] * s;
                float g = ag[mt][nt][r] * s;
                float o = h * g / (1.0f + __expf(-g));   // h * silu(g)
                out[(size_t)m * NOUT + n] = o;
            }
}

// ---------------------------------------------------------------------------
extern "C" void kernel_launch(void* const* d_in, const int* in_sizes, int n_in,
                              void* d_out, int out_size, void* d_ws, size_t ws_size,
                              hipStream_t stream) {
    const float* x = (const float*)d_in[0];
    const float* w = (const float*)d_in[1];
    float* out = (float*)d_out;   // reference output dtype is float32

    char* ws = (char*)d_ws;
    float* sc = (float*)ws;                                   // [0]=sum|W|
    _Float16* qA = (_Float16*)(ws + 4096);                    // 32 MB normed f16
    _Float16* wB = (_Float16*)(ws + 4096 + 33554432);         // 32 MB ternary f16

    hipMemsetAsync(sc, 0, 4, stream);

    prep_k<<<N_TOK + 1024, 256, 0, stream>>>(x, w, qA, sc);
    ternW_k<<<2048, 256, 0, stream>>>(w, sc, wB);

    dim3 grid(NOUT / 128, N_TOK / 128);  // 32 x 64
    gemm_glu_k<<<grid, 256, 0, stream>>>(qA, wB, sc, out);
}

// Round 4
// 484.197 us; speedup vs baseline: 1.2277x; 1.0135x over previous
//
#include <hip/hip_runtime.h>
#include <hip/hip_bf16.h>
#include <cstdint>

// ---------------------------------------------------------------------------
// BitLinear GLU: x[8192,2048] f32, W[8192,2048] f32 -> out[8192,4096] f32
//   Identity: out = (normed @ w_bin^T) * w_gamma  -- input_gamma cancels
//   (clip at +-128 only binds within 1e-7 of the global max: delta ~ 5e-9).
//   3 graph nodes, no memset, no atomics:
//   K1: per-row LN -> normed (f16)  ||  per-block partial sums of |W|
//   K2: reduce partials -> wg; w_bin = clip(round(W/(wg+1e-7)),-1,1) (f16)
//   K3: C = normed @ w_bin^T; out = C_h * silu(C_g) * wg  (fused dual-half)
// ---------------------------------------------------------------------------

#define N_TOK   8192
#define DIMIN   2048
#define DIMOUT  8192
#define NOUT    4096   // DIMOUT/2
#define W_ELEMS 16777216.0f
#define NPART   1024

typedef _Float16 f16x8 __attribute__((ext_vector_type(8)));
typedef _Float16 f16x4 __attribute__((ext_vector_type(4)));
typedef float    f32x4 __attribute__((ext_vector_type(4)));

// ---------------- K1: LN rows -> f16  ||  |W| partial sums ------------------
__global__ __launch_bounds__(256) void ln_wsum_k(
    const float* __restrict__ x, const float* __restrict__ w,
    _Float16* __restrict__ qA, float* __restrict__ wpart) {
    const int b = blockIdx.x;
    const int t = threadIdx.x;
    if (b < N_TOK) {
        __shared__ float sh[8];
        const float4* xr = (const float4*)(x + (size_t)b * DIMIN);
        float4 a = xr[2 * t];
        float4 c = xr[2 * t + 1];
        float s = (a.x + a.y) + (a.z + a.w) + ((c.x + c.y) + (c.z + c.w));
#pragma unroll
        for (int o = 32; o > 0; o >>= 1) s += __shfl_down(s, o, 64);
        if ((t & 63) == 0) sh[t >> 6] = s;
        __syncthreads();
        const float mu = (sh[0] + sh[1] + sh[2] + sh[3]) * (1.0f / DIMIN);

        float d0 = a.x - mu, d1 = a.y - mu, d2 = a.z - mu, d3 = a.w - mu;
        float d4 = c.x - mu, d5 = c.y - mu, d6 = c.z - mu, d7 = c.w - mu;
        float ss = d0*d0 + d1*d1 + d2*d2 + d3*d3 + d4*d4 + d5*d5 + d6*d6 + d7*d7;
#pragma unroll
        for (int o = 32; o > 0; o >>= 1) ss += __shfl_down(ss, o, 64);
        if ((t & 63) == 0) sh[4 + (t >> 6)] = ss;
        __syncthreads();
        const float var = (sh[4] + sh[5] + sh[6] + sh[7]) * (1.0f / DIMIN);
        const float r = rsqrtf(var + 1e-5f);
        f16x8 o;
        o[0] = (_Float16)(d0 * r); o[1] = (_Float16)(d1 * r);
        o[2] = (_Float16)(d2 * r); o[3] = (_Float16)(d3 * r);
        o[4] = (_Float16)(d4 * r); o[5] = (_Float16)(d5 * r);
        o[6] = (_Float16)(d6 * r); o[7] = (_Float16)(d7 * r);
        ((f16x8*)(qA + (size_t)b * DIMIN))[t] = o;
    } else {
        const int p = b - N_TOK;                 // 0..1023
        float acc = 0.0f;
        const float4* w4 = (const float4*)w;
        for (unsigned i = (unsigned)p * 256u + t; i < 4194304u; i += 262144u) {
            float4 v = w4[i];                    // 16 iterations
            acc += (fabsf(v.x) + fabsf(v.y)) + (fabsf(v.z) + fabsf(v.w));
        }
        __shared__ float shw[4];
#pragma unroll
        for (int o = 32; o > 0; o >>= 1) acc += __shfl_down(acc, o, 64);
        if ((t & 63) == 0) shw[t >> 6] = acc;
        __syncthreads();
        if (t == 0) wpart[p] = (shw[0] + shw[1]) + (shw[2] + shw[3]);
    }
}

// ---------------- K2: reduce partials, ternarize W to f16 -------------------
__global__ __launch_bounds__(256) void ternW_k(
    const float* __restrict__ w, const float* __restrict__ wpart,
    float* __restrict__ sc, _Float16* __restrict__ q) {
    const int t = threadIdx.x;
    __shared__ float sh[4];
    float4 p = ((const float4*)wpart)[t];        // 256 threads cover 1024 partials
    float acc = (p.x + p.y) + (p.z + p.w);
#pragma unroll
    for (int o = 32; o > 0; o >>= 1) acc += __shfl_down(acc, o, 64);
    if ((t & 63) == 0) sh[t >> 6] = acc;
    __syncthreads();
    const float wg = ((sh[0] + sh[1]) + (sh[2] + sh[3])) * (1.0f / W_ELEMS);
    if (blockIdx.x == 0 && t == 0) sc[0] = wg;   // for GEMM epilogue
    const float invw = 1.0f / (wg + 1e-7f);
    for (unsigned i = blockIdx.x * 256u + t; i < 4194304u; i += 262144u) {
        float4 v = ((const float4*)w)[i];        // 16 iterations (1024 blocks)
        f16x4 o;
        o.x = (_Float16)fminf(fmaxf(rintf(v.x * invw), -1.0f), 1.0f);
        o.y = (_Float16)fminf(fmaxf(rintf(v.y * invw), -1.0f), 1.0f);
        o.z = (_Float16)fminf(fmaxf(rintf(v.z * invw), -1.0f), 1.0f);
        o.w = (_Float16)fminf(fmaxf(rintf(v.w * invw), -1.0f), 1.0f);
        ((f16x4*)q)[i] = o;
    }
}

// ---------------- K3: fused GEMM (both halves) + SiLU gate ------------------
__device__ __forceinline__ void ld16(const _Float16* g, _Float16* l) {
    __builtin_amdgcn_global_load_lds(
        (const __attribute__((address_space(1))) unsigned int*)g,
        (__attribute__((address_space(3))) unsigned int*)l, 16, 0, 0);
}

__global__ __launch_bounds__(256, 2) void gemm_glu_k(
    const _Float16* __restrict__ Aq, const _Float16* __restrict__ Wq,
    const float* __restrict__ sc, float* __restrict__ out) {
    // 128 (m) x 128 (n of OUT) block tile; C_h from W rows n0.., C_g from
    // W rows n0+4096.. ; BK=32; LDS 3x8KB single-buffered (m97 structure).
    // 16B-granule XOR swizzle kills the 8-way bank conflict on frag reads:
    //   element (r, kg) stored at granule (kg ^ ((r>>1)&3)) of row r.
    __shared__ __align__(16) _Float16 smem[3 * 4096];
    _Float16* As = smem;
    _Float16* Bh = smem + 4096;
    _Float16* Bg = smem + 8192;

    const int tid  = threadIdx.x;
    const int wave = tid >> 6;
    const int lane = tid & 63;
    const int m0 = blockIdx.y << 7;
    const int n0 = blockIdx.x << 7;

    const int srow = wave * 16 + (lane >> 2);
    const int scol = (((lane & 3) ^ ((lane >> 3) & 3)) << 3);
    const _Float16* ga0 = Aq + (size_t)(m0 + srow) * DIMIN + scol;
    const _Float16* ga1 = ga0 + 64 * DIMIN;
    const _Float16* gh0 = Wq + (size_t)(n0 + srow) * DIMIN + scol;
    const _Float16* gh1 = gh0 + 64 * DIMIN;
    const _Float16* gg0 = Wq + (size_t)(n0 + NOUT + srow) * DIMIN + scol;
    const _Float16* gg1 = gg0 + 64 * DIMIN;

    _Float16* const da0 = As + wave * 512;          // wave-uniform LDS bases
    _Float16* const da1 = As + 2048 + wave * 512;
    _Float16* const dh0 = Bh + wave * 512;
    _Float16* const dh1 = Bh + 2048 + wave * 512;
    _Float16* const dg0 = Bg + wave * 512;
    _Float16* const dg1 = Bg + 2048 + wave * 512;

    const int wm = (wave >> 1) * 64;   // wave's 64x64 quadrant
    const int wn = (wave & 1) * 64;
    const int fr = lane & 15;
    const int fswz = (((lane >> 4) ^ ((fr >> 1) & 3)) << 3);

    f32x4 zero = {0.0f, 0.0f, 0.0f, 0.0f};
    f32x4 ah[4][4], ag[4][4];
#pragma unroll
    for (int i = 0; i < 4; ++i)
#pragma unroll
        for (int j = 0; j < 4; ++j) { ah[i][j] = zero; ag[i][j] = zero; }

    for (int kk = 0; kk < DIMIN / 32; ++kk) {
        __syncthreads();
        ld16(ga0, da0); ld16(ga1, da1);
        ld16(gh0, dh0); ld16(gh1, dh1);
        ld16(gg0, dg0); ld16(gg1, dg1);
        ga0 += 32; ga1 += 32; gh0 += 32; gh1 += 32; gg0 += 32; gg1 += 32;
        __syncthreads();

        f16x8 af[4], bhf[4], bgf[4];
#pragma unroll
        for (int t = 0; t < 4; ++t) {
            af[t]  = *(const f16x8*)(As + (wm + t * 16 + fr) * 32 + fswz);
            bhf[t] = *(const f16x8*)(Bh + (wn + t * 16 + fr) * 32 + fswz);
            bgf[t] = *(const f16x8*)(Bg + (wn + t * 16 + fr) * 32 + fswz);
        }
#pragma unroll
        for (int mt = 0; mt < 4; ++mt)
#pragma unroll
            for (int nt = 0; nt < 4; ++nt) {
                ah[mt][nt] = __builtin_amdgcn_mfma_f32_16x16x32_f16(af[mt], bhf[nt], ah[mt][nt], 0, 0, 0);
                ag[mt][nt] = __builtin_amdgcn_mfma_f32_16x16x32_f16(af[mt], bgf[nt], ag[mt][nt], 0, 0, 0);
            }
    }

    const float s = sc[0];            // w_gamma
    const int er = (lane >> 4) * 4;   // C/D: col = lane&15, row = (lane>>4)*4 + r
#pragma unroll
    for (int mt = 0; mt < 4; ++mt)
#pragma unroll
        for (int nt = 0; nt < 4; ++nt)
#pragma unroll
            for (int r = 0; r < 4; ++r) {
                int m = m0 + wm + mt * 16 + er + r;
                int n = n0 + wn + nt * 16 + fr;
                float h = ah[mt][nt][r] * s;
                float g = ag[mt][nt][r] * s;
                float o = h * g / (1.0f + __expf(-g));   // h * silu(g)
                out[(size_t)m * NOUT + n] = o;
            }
}

// ---------------------------------------------------------------------------
extern "C" void kernel_launch(void* const* d_in, const int* in_sizes, int n_in,
                              void* d_out, int out_size, void* d_ws, size_t ws_size,
                              hipStream_t stream) {
    const float* x = (const float*)d_in[0];
    const float* w = (const float*)d_in[1];
    float* out = (float*)d_out;   // reference output dtype is float32

    char* ws = (char*)d_ws;
    float* sc    = (float*)ws;                                // [0] = wg
    float* wpart = (float*)(ws + 4096);                       // 1024 partials
    _Float16* qA = (_Float16*)(ws + 16384);                   // 32 MB normed f16
    _Float16* wB = (_Float16*)(ws + 16384 + 33554432);        // 32 MB ternary f16

    ln_wsum_k<<<N_TOK + NPART, 256, 0, stream>>>(x, w, qA, wpart);
    ternW_k<<<NPART, 256, 0, stream>>>(w, wpart, sc, wB);

    dim3 grid(NOUT / 128, N_TOK / 128);  // 32 x 64
    gemm_glu_k<<<grid, 256, 0, stream>>>(qA, wB, sc, out);
}